// Round 2
// baseline (7264.924 us; speedup 1.0000x reference)
//
#include <hip/hip_runtime.h>
#include <hip/hip_bf16.h>
#include <math.h>

#define NEG_SLOPE 0.2f
// order-preserving map of -inf
#define NEG_INF_ORD 0x007FFFFFu

__device__ __forceinline__ unsigned f2o(float f) {
    unsigned u = __float_as_uint(f);
    return (u & 0x80000000u) ? ~u : (u | 0x80000000u);
}
__device__ __forceinline__ float o2f(unsigned u) {
    return (u & 0x80000000u) ? __uint_as_float(u & 0x7FFFFFFFu) : __uint_as_float(~u);
}
__device__ __forceinline__ float lrelu(float x) { return x > 0.f ? x : NEG_SLOPE * x; }

// -------------------- init all accumulators --------------------
__global__ void init_kernel(unsigned* __restrict__ m1, float* __restrict__ denom1,
                            float* __restrict__ out1, unsigned* __restrict__ m2,
                            float* __restrict__ denom2, float* __restrict__ out2, int N) {
    int i = blockIdx.x * blockDim.x + threadIdx.x;
    if (i < N * 32) out1[i] = 0.f;
    if (i < N * 4) { m1[i] = NEG_INF_ORD; denom1[i] = 0.f; }
    if (i < N)     { m2[i] = NEG_INF_ORD; denom2[i] = 0.f; }
    if (i < N * 2) out2[i] = 0.f;
}

// -------------------- layer 1 node transform --------------------
__global__ void node1_kernel(const float* __restrict__ x,
                             const float* __restrict__ W1,
                             const float* __restrict__ asrc,
                             const float* __restrict__ adst,
                             float* __restrict__ h1,      // [N,32]
                             float4* __restrict__ al_src, // [N] of 4 heads
                             float4* __restrict__ al_dst, int N) {
    __shared__ float sW[64], sA[32], sD[32];
    int t = threadIdx.x;
    if (t < 64) sW[t] = W1[t];
    if (t < 32) { sA[t] = asrc[t]; sD[t] = adst[t]; }
    __syncthreads();
    int n = blockIdx.x * blockDim.x + t;
    if (n >= N) return;
    float x0 = x[2 * n];
    float x1 = x[2 * n + 1];
    float as[4] = {0.f, 0.f, 0.f, 0.f};
    float ad[4] = {0.f, 0.f, 0.f, 0.f};
#pragma unroll
    for (int c = 0; c < 32; c++) {
        float v = x0 * sW[c] + x1 * sW[32 + c];
        h1[n * 32 + c] = v;
        int h = c >> 3;
        as[h] += v * sA[c];
        ad[h] += v * sD[c];
    }
    al_src[n] = make_float4(as[0], as[1], as[2], as[3]);
    al_dst[n] = make_float4(ad[0], ad[1], ad[2], ad[3]);
}

// -------------------- layer 1 edge passes --------------------
__device__ __forceinline__ void edge_ids1(const int* src, const int* dst, int e, int E,
                                          int& s, int& d) {
    if (e < E) { s = src[e]; d = dst[e]; } else { s = e - E; d = e - E; }
}

__global__ void edge1_max(const int* __restrict__ src, const int* __restrict__ dst,
                          const float4* __restrict__ al_src, const float4* __restrict__ al_dst,
                          unsigned* __restrict__ m, int E, int N) {
    int e = blockIdx.x * blockDim.x + threadIdx.x;
    if (e >= E + N) return;
    int s, d;
    edge_ids1(src, dst, e, E, s, d);
    float4 a = al_src[s], b = al_dst[d];
    atomicMax(&m[d * 4 + 0], f2o(lrelu(a.x + b.x)));
    atomicMax(&m[d * 4 + 1], f2o(lrelu(a.y + b.y)));
    atomicMax(&m[d * 4 + 2], f2o(lrelu(a.z + b.z)));
    atomicMax(&m[d * 4 + 3], f2o(lrelu(a.w + b.w)));
}

__global__ void edge1_sum(const int* __restrict__ src, const int* __restrict__ dst,
                          const float4* __restrict__ al_src, const float4* __restrict__ al_dst,
                          const unsigned* __restrict__ m, float* __restrict__ denom,
                          int E, int N) {
    int e = blockIdx.x * blockDim.x + threadIdx.x;
    if (e >= E + N) return;
    int s, d;
    edge_ids1(src, dst, e, E, s, d);
    float4 a = al_src[s], b = al_dst[d];
    atomicAdd(&denom[d * 4 + 0], expf(lrelu(a.x + b.x) - o2f(m[d * 4 + 0])));
    atomicAdd(&denom[d * 4 + 1], expf(lrelu(a.y + b.y) - o2f(m[d * 4 + 1])));
    atomicAdd(&denom[d * 4 + 2], expf(lrelu(a.z + b.z) - o2f(m[d * 4 + 2])));
    atomicAdd(&denom[d * 4 + 3], expf(lrelu(a.w + b.w) - o2f(m[d * 4 + 3])));
}

__global__ void edge1_agg(const int* __restrict__ src, const int* __restrict__ dst,
                          const float4* __restrict__ al_src, const float4* __restrict__ al_dst,
                          const unsigned* __restrict__ m, const float* __restrict__ denom,
                          const float4* __restrict__ h1,  // [N*8] float4s
                          float* __restrict__ out1, int E, int N) {
    int e = blockIdx.x * blockDim.x + threadIdx.x;
    if (e >= E + N) return;
    int s, d;
    edge_ids1(src, dst, e, E, s, d);
    float4 a = al_src[s], b = al_dst[d];
    float alpha[4];
    alpha[0] = expf(lrelu(a.x + b.x) - o2f(m[d * 4 + 0])) / (denom[d * 4 + 0] + 1e-16f);
    alpha[1] = expf(lrelu(a.y + b.y) - o2f(m[d * 4 + 1])) / (denom[d * 4 + 1] + 1e-16f);
    alpha[2] = expf(lrelu(a.z + b.z) - o2f(m[d * 4 + 2])) / (denom[d * 4 + 2] + 1e-16f);
    alpha[3] = expf(lrelu(a.w + b.w) - o2f(m[d * 4 + 3])) / (denom[d * 4 + 3] + 1e-16f);
#pragma unroll
    for (int k = 0; k < 8; k++) {
        float4 hv = h1[s * 8 + k];
        int base = d * 32 + k * 4;
        int head = k >> 1;
        float al = alpha[head];
        atomicAdd(&out1[base + 0], hv.x * al);
        atomicAdd(&out1[base + 1], hv.y * al);
        atomicAdd(&out1[base + 2], hv.z * al);
        atomicAdd(&out1[base + 3], hv.w * al);
    }
}

// -------------------- layer 2 node transform --------------------
__global__ void node2_kernel(const float* __restrict__ out1,
                             const float* __restrict__ b1,
                             const float* __restrict__ W2,
                             const float* __restrict__ as2,
                             const float* __restrict__ ad2,
                             float2* __restrict__ h2,   // [N]
                             float* __restrict__ al2s, float* __restrict__ al2d, int N) {
    __shared__ float sW[64], sB[32], sAS[2], sAD[2];
    int t = threadIdx.x;
    if (t < 64) sW[t] = W2[t];
    if (t < 32) sB[t] = b1[t];
    if (t < 2) { sAS[t] = as2[t]; sAD[t] = ad2[t]; }
    __syncthreads();
    int n = blockIdx.x * blockDim.x + t;
    if (n >= N) return;
    float h20 = 0.f, h21 = 0.f;
#pragma unroll
    for (int c = 0; c < 32; c++) {
        float v = out1[n * 32 + c] + sB[c];
        v = v > 0.f ? v : expm1f(v);  // elu
        h20 += v * sW[c * 2 + 0];
        h21 += v * sW[c * 2 + 1];
    }
    h2[n] = make_float2(h20, h21);
    al2s[n] = h20 * sAS[0] + h21 * sAS[1];
    al2d[n] = h20 * sAD[0] + h21 * sAD[1];
}

// -------------------- layer 2 edge passes --------------------
__global__ void edge2_max(const int* __restrict__ src, const int* __restrict__ dst,
                          const float* __restrict__ al2s, const float* __restrict__ al2d,
                          unsigned* __restrict__ m2, int E, int N) {
    int e = blockIdx.x * blockDim.x + threadIdx.x;
    if (e >= E + N) return;
    int s, d;
    edge_ids1(src, dst, e, E, s, d);
    atomicMax(&m2[d], f2o(lrelu(al2s[s] + al2d[d])));
}

__global__ void edge2_sum(const int* __restrict__ src, const int* __restrict__ dst,
                          const float* __restrict__ al2s, const float* __restrict__ al2d,
                          const unsigned* __restrict__ m2, float* __restrict__ denom2,
                          int E, int N) {
    int e = blockIdx.x * blockDim.x + threadIdx.x;
    if (e >= E + N) return;
    int s, d;
    edge_ids1(src, dst, e, E, s, d);
    atomicAdd(&denom2[d], expf(lrelu(al2s[s] + al2d[d]) - o2f(m2[d])));
}

__global__ void edge2_agg(const int* __restrict__ src, const int* __restrict__ dst,
                          const float* __restrict__ al2s, const float* __restrict__ al2d,
                          const unsigned* __restrict__ m2, const float* __restrict__ denom2,
                          const float2* __restrict__ h2, float* __restrict__ out2,
                          int E, int N) {
    int e = blockIdx.x * blockDim.x + threadIdx.x;
    if (e >= E + N) return;
    int s, d;
    edge_ids1(src, dst, e, E, s, d);
    float alpha = expf(lrelu(al2s[s] + al2d[d]) - o2f(m2[d])) / (denom2[d] + 1e-16f);
    float2 hv = h2[s];
    atomicAdd(&out2[d * 2 + 0], hv.x * alpha);
    atomicAdd(&out2[d * 2 + 1], hv.y * alpha);
}

// -------------------- finalize --------------------
__global__ void final_kernel(const float* __restrict__ out2,
                             const float* __restrict__ b2,
                             float* __restrict__ out, int N) {
    int i = blockIdx.x * blockDim.x + threadIdx.x;
    if (i >= 2 * N) return;
    out[i] = out2[i] + b2[i & 1];
}

extern "C" void kernel_launch(void* const* d_in, const int* in_sizes, int n_in,
                              void* d_out, int out_size, void* d_ws, size_t ws_size,
                              hipStream_t stream) {
    const float* x     = (const float*)d_in[0];
    const int*   eidx  = (const int*)d_in[1];
    // d_in[2] edge_attr unused
    const float* W1    = (const float*)d_in[3];
    const float* asrc1 = (const float*)d_in[4];
    const float* adst1 = (const float*)d_in[5];
    const float* b1    = (const float*)d_in[6];
    const float* W2    = (const float*)d_in[7];
    const float* asrc2 = (const float*)d_in[8];
    const float* adst2 = (const float*)d_in[9];
    const float* b2    = (const float*)d_in[10];

    const int N = in_sizes[0] / 2;   // 100000
    const int E = in_sizes[1] / 2;   // 3200000
    const int* src = eidx;
    const int* dst = eidx + E;

    // workspace layout (floats)
    float* w = (float*)d_ws;
    float*    h1     = w;                               // 32N
    float4*   al_s1  = (float4*)(w + 32 * (size_t)N);   // 4N floats
    float4*   al_d1  = (float4*)(w + 36 * (size_t)N);   // 4N
    unsigned* m1     = (unsigned*)(w + 40 * (size_t)N); // 4N
    float*    den1   = w + 44 * (size_t)N;              // 4N
    float*    out1   = w + 48 * (size_t)N;              // 32N
    float2*   h2     = (float2*)(w + 80 * (size_t)N);   // 2N
    float*    al2s   = w + 82 * (size_t)N;              // N
    float*    al2d   = w + 83 * (size_t)N;              // N
    unsigned* m2     = (unsigned*)(w + 84 * (size_t)N); // N
    float*    den2   = w + 85 * (size_t)N;              // N
    float*    out2   = w + 86 * (size_t)N;              // 2N

    const int B = 256;
    int gInit = (32 * N + B - 1) / B;
    int gNode = (N + B - 1) / B;
    int gEdge = (E + N + B - 1) / B;
    int gFin  = (2 * N + B - 1) / B;

    init_kernel<<<gInit, B, 0, stream>>>(m1, den1, out1, m2, den2, out2, N);
    node1_kernel<<<gNode, B, 0, stream>>>(x, W1, asrc1, adst1, h1, al_s1, al_d1, N);
    edge1_max<<<gEdge, B, 0, stream>>>(src, dst, al_s1, al_d1, m1, E, N);
    edge1_sum<<<gEdge, B, 0, stream>>>(src, dst, al_s1, al_d1, m1, den1, E, N);
    edge1_agg<<<gEdge, B, 0, stream>>>(src, dst, al_s1, al_d1, m1, den1,
                                       (const float4*)h1, out1, E, N);
    node2_kernel<<<gNode, B, 0, stream>>>(out1, b1, W2, asrc2, adst2, h2, al2s, al2d, N);
    edge2_max<<<gEdge, B, 0, stream>>>(src, dst, al2s, al2d, m2, E, N);
    edge2_sum<<<gEdge, B, 0, stream>>>(src, dst, al2s, al2d, m2, den2, E, N);
    edge2_agg<<<gEdge, B, 0, stream>>>(src, dst, al2s, al2d, m2, den2, h2, out2, E, N);
    final_kernel<<<gFin, B, 0, stream>>>(out2, b2, (float*)d_out, N);
}

// Round 3
// 723.909 us; speedup vs baseline: 10.0357x; 10.0357x over previous
//
#include <hip/hip_runtime.h>
#include <hip/hip_bf16.h>
#include <math.h>

#define NEG_SLOPE 0.2f

__device__ __forceinline__ float lrelu(float x) { return x > 0.f ? x : NEG_SLOPE * x; }

// ==================== CSR build ====================
__global__ void init_deg(int* __restrict__ deg, int N) {
    int i = blockIdx.x * blockDim.x + threadIdx.x;
    if (i < N) deg[i] = 1;  // self-loop
}

__global__ void hist_kernel(const int* __restrict__ dst, int* __restrict__ deg, int E) {
    int e = blockIdx.x * blockDim.x + threadIdx.x;
    if (e < E) atomicAdd(&deg[dst[e]], 1);
}

// per-block sums of 1024-element chunks
__global__ void scan_partial(const int* __restrict__ deg, int* __restrict__ partial, int N) {
    __shared__ int sd[256];
    int t = threadIdx.x;
    int base = blockIdx.x * 1024 + t * 4;
    int s = 0;
#pragma unroll
    for (int k = 0; k < 4; k++) if (base + k < N) s += deg[base + k];
    sd[t] = s;
    __syncthreads();
    for (int off = 128; off > 0; off >>= 1) {
        if (t < off) sd[t] += sd[t + off];
        __syncthreads();
    }
    if (t == 0) partial[blockIdx.x] = sd[0];
}

// single-block exclusive scan of block partials (nb <= 256)
__global__ void scan_single(int* __restrict__ partial, int nb) {
    __shared__ int sd[256];
    int t = threadIdx.x;
    sd[t] = (t < nb) ? partial[t] : 0;
    __syncthreads();
    for (int off = 1; off < 256; off <<= 1) {
        int u = (t >= off) ? sd[t - off] : 0;
        __syncthreads();
        sd[t] += u;
        __syncthreads();
    }
    if (t < nb) partial[t] = (t == 0) ? 0 : sd[t - 1];
}

// local exclusive scan + block offset -> row_start; place self-loop, init cursor
__global__ void scan_final(const int* __restrict__ deg, const int* __restrict__ partial,
                           int* __restrict__ row_start, int* __restrict__ cursor,
                           int* __restrict__ csr_src, int N) {
    __shared__ int sd[256];
    int t = threadIdx.x;
    int base = blockIdx.x * 1024 + t * 4;
    int v[4];
    int s = 0;
#pragma unroll
    for (int k = 0; k < 4; k++) {
        v[k] = (base + k < N) ? deg[base + k] : 0;
        s += v[k];
    }
    sd[t] = s;
    __syncthreads();
    for (int off = 1; off < 256; off <<= 1) {
        int u = (t >= off) ? sd[t - off] : 0;
        __syncthreads();
        sd[t] += u;
        __syncthreads();
    }
    int offset = partial[blockIdx.x] + ((t == 0) ? 0 : sd[t - 1]);
#pragma unroll
    for (int k = 0; k < 4; k++) {
        int i = base + k;
        if (i < N) {
            row_start[i] = offset;
            csr_src[offset] = i;       // self-loop first
            cursor[i] = offset + 1;
            if (i == N - 1) row_start[N] = offset + v[k];
            offset += v[k];
        }
    }
}

__global__ void scatter_kernel(const int* __restrict__ src, const int* __restrict__ dst,
                               int* __restrict__ cursor, int* __restrict__ csr_src, int E) {
    int e = blockIdx.x * blockDim.x + threadIdx.x;
    if (e >= E) return;
    int d = dst[e];
    int pos = atomicAdd(&cursor[d], 1);
    csr_src[pos] = src[e];
}

// ==================== layer 1 node transform ====================
__global__ void node1_kernel(const float* __restrict__ x,
                             const float* __restrict__ W1,
                             const float* __restrict__ asrc,
                             const float* __restrict__ adst,
                             float* __restrict__ h1,      // [N,32]
                             float4* __restrict__ al_src, // [N] x 4 heads
                             float4* __restrict__ al_dst, int N) {
    __shared__ float sW[64], sA[32], sD[32];
    int t = threadIdx.x;
    if (t < 64) sW[t] = W1[t];
    if (t < 32) { sA[t] = asrc[t]; sD[t] = adst[t]; }
    __syncthreads();
    int n = blockIdx.x * blockDim.x + t;
    if (n >= N) return;
    float x0 = x[2 * n];
    float x1 = x[2 * n + 1];
    float as[4] = {0.f, 0.f, 0.f, 0.f};
    float ad[4] = {0.f, 0.f, 0.f, 0.f};
#pragma unroll
    for (int c = 0; c < 32; c++) {
        float v = x0 * sW[c] + x1 * sW[32 + c];
        h1[n * 32 + c] = v;
        int h = c >> 3;
        as[h] += v * sA[c];
        ad[h] += v * sD[c];
    }
    al_src[n] = make_float4(as[0], as[1], as[2], as[3]);
    al_dst[n] = make_float4(ad[0], ad[1], ad[2], ad[3]);
}

// ==================== layer 1 aggregate: one wave per dst ====================
__global__ void agg1_kernel(const int* __restrict__ row_start, const int* __restrict__ csr_src,
                            const float4* __restrict__ al_src, const float4* __restrict__ al_dst,
                            const float* __restrict__ al_src_f,  // same buffer as floats
                            const float* __restrict__ h1,
                            float* __restrict__ out1, int N) {
    int wid = (blockIdx.x * blockDim.x + threadIdx.x) >> 6;
    int lane = threadIdx.x & 63;
    if (wid >= N) return;
    int d = wid;
    int row = row_start[d];
    int deg = row_start[d + 1] - row;
    float4 ald = al_dst[d];

    // ---- pass 1: per-head max over incoming edges ----
    float mx0 = -1e30f, mx1 = -1e30f, mx2 = -1e30f, mx3 = -1e30f;
    for (int i = lane; i < deg; i += 64) {
        int s = csr_src[row + i];
        float4 as = al_src[s];
        mx0 = fmaxf(mx0, lrelu(as.x + ald.x));
        mx1 = fmaxf(mx1, lrelu(as.y + ald.y));
        mx2 = fmaxf(mx2, lrelu(as.z + ald.z));
        mx3 = fmaxf(mx3, lrelu(as.w + ald.w));
    }
#pragma unroll
    for (int off = 32; off > 0; off >>= 1) {
        mx0 = fmaxf(mx0, __shfl_xor(mx0, off));
        mx1 = fmaxf(mx1, __shfl_xor(mx1, off));
        mx2 = fmaxf(mx2, __shfl_xor(mx2, off));
        mx3 = fmaxf(mx3, __shfl_xor(mx3, off));
    }

    // ---- pass 2: numerator + denominator together ----
    int c = lane & 31;        // channel
    int h = c >> 3;           // head
    int half = lane >> 5;     // 2 edges in flight
    float mh = (h == 0) ? mx0 : (h == 1) ? mx1 : (h == 2) ? mx2 : mx3;
    float aldh = (h == 0) ? ald.x : (h == 1) ? ald.y : (h == 2) ? ald.z : ald.w;
    float acc = 0.f, wsum = 0.f;
    for (int j = half; j < deg; j += 2) {
        int s = csr_src[row + j];
        float ash = al_src_f[s * 4 + h];
        float w = __expf(lrelu(ash + aldh) - mh);
        acc += h1[s * 32 + c] * w;
        wsum += w;
    }
    acc += __shfl_xor(acc, 32);
    wsum += __shfl_xor(wsum, 32);
    if (lane < 32) out1[d * 32 + c] = acc / (wsum + 1e-16f);
}

// ==================== layer 2 node transform ====================
__global__ void node2_kernel(const float* __restrict__ out1,
                             const float* __restrict__ b1,
                             const float* __restrict__ W2,
                             const float* __restrict__ as2,
                             const float* __restrict__ ad2,
                             float2* __restrict__ h2,   // [N]
                             float* __restrict__ al2s, float* __restrict__ al2d, int N) {
    __shared__ float sW[64], sB[32], sAS[2], sAD[2];
    int t = threadIdx.x;
    if (t < 64) sW[t] = W2[t];
    if (t < 32) sB[t] = b1[t];
    if (t < 2) { sAS[t] = as2[t]; sAD[t] = ad2[t]; }
    __syncthreads();
    int n = blockIdx.x * blockDim.x + t;
    if (n >= N) return;
    float h20 = 0.f, h21 = 0.f;
#pragma unroll
    for (int c = 0; c < 32; c++) {
        float v = out1[n * 32 + c] + sB[c];
        v = v > 0.f ? v : expm1f(v);  // elu
        h20 += v * sW[c * 2 + 0];
        h21 += v * sW[c * 2 + 1];
    }
    h2[n] = make_float2(h20, h21);
    al2s[n] = h20 * sAS[0] + h21 * sAS[1];
    al2d[n] = h20 * sAD[0] + h21 * sAD[1];
}

// ==================== layer 2 aggregate: one wave per dst, writes d_out ====================
__global__ void agg2_kernel(const int* __restrict__ row_start, const int* __restrict__ csr_src,
                            const float* __restrict__ al2s, const float* __restrict__ al2d,
                            const float2* __restrict__ h2, const float* __restrict__ b2,
                            float* __restrict__ out, int N) {
    int wid = (blockIdx.x * blockDim.x + threadIdx.x) >> 6;
    int lane = threadIdx.x & 63;
    if (wid >= N) return;
    int d = wid;
    int row = row_start[d];
    int deg = row_start[d + 1] - row;
    float ald = al2d[d];

    float mx = -1e30f;
    for (int i = lane; i < deg; i += 64) {
        int s = csr_src[row + i];
        mx = fmaxf(mx, lrelu(al2s[s] + ald));
    }
#pragma unroll
    for (int off = 32; off > 0; off >>= 1) mx = fmaxf(mx, __shfl_xor(mx, off));

    float wsum = 0.f, ax = 0.f, ay = 0.f;
    for (int i = lane; i < deg; i += 64) {
        int s = csr_src[row + i];
        float w = __expf(lrelu(al2s[s] + ald) - mx);
        float2 hv = h2[s];
        wsum += w;
        ax += w * hv.x;
        ay += w * hv.y;
    }
#pragma unroll
    for (int off = 32; off > 0; off >>= 1) {
        wsum += __shfl_xor(wsum, off);
        ax += __shfl_xor(ax, off);
        ay += __shfl_xor(ay, off);
    }
    if (lane == 0) {
        float inv = 1.f / (wsum + 1e-16f);
        out[d * 2 + 0] = ax * inv + b2[0];
        out[d * 2 + 1] = ay * inv + b2[1];
    }
}

extern "C" void kernel_launch(void* const* d_in, const int* in_sizes, int n_in,
                              void* d_out, int out_size, void* d_ws, size_t ws_size,
                              hipStream_t stream) {
    const float* x     = (const float*)d_in[0];
    const int*   eidx  = (const int*)d_in[1];
    // d_in[2] edge_attr unused
    const float* W1    = (const float*)d_in[3];
    const float* asrc1 = (const float*)d_in[4];
    const float* adst1 = (const float*)d_in[5];
    const float* b1    = (const float*)d_in[6];
    const float* W2    = (const float*)d_in[7];
    const float* asrc2 = (const float*)d_in[8];
    const float* adst2 = (const float*)d_in[9];
    const float* b2    = (const float*)d_in[10];

    const int N = in_sizes[0] / 2;   // 100000
    const int E = in_sizes[1] / 2;   // 3200000
    const int* src = eidx;
    const int* dst = eidx + E;

    // -------- workspace layout --------
    float* w = (float*)d_ws;
    float*  h1    = w;                                // 32N floats (reused for layer-2 tensors)
    float2* h2    = (float2*)h1;                      // 2N floats (alias, used after h1 dead)
    float*  al2s  = h1 + 2 * (size_t)N;               // N  (alias inside h1 region)
    float*  al2d  = h1 + 3 * (size_t)N;               // N  (alias inside h1 region)
    float4* al_s1 = (float4*)(w + 32 * (size_t)N);    // 4N floats
    float4* al_d1 = (float4*)(w + 36 * (size_t)N);    // 4N
    float*  out1  = w + 40 * (size_t)N;               // 32N
    int* ip        = (int*)(w + 72 * (size_t)N);
    int* deg       = ip;                              // N
    int* row_start = ip + (size_t)N;                  // N+1
    int* cursor    = ip + 2 * (size_t)N + 1;          // N
    int* partial   = ip + 3 * (size_t)N + 1;          // 256
    int* csr_src   = ip + 3 * (size_t)N + 1 + 256;    // E+N

    const int B = 256;
    const int nb = (N + 1023) / 1024;   // scan blocks (98 <= 256)
    int gN = (N + B - 1) / B;
    int gE = (E + B - 1) / B;
    int gW = (N + 3) / 4;               // 1 wave per dst, 4 waves/block

    // CSR build
    init_deg<<<gN, B, 0, stream>>>(deg, N);
    hist_kernel<<<gE, B, 0, stream>>>(dst, deg, E);
    scan_partial<<<nb, B, 0, stream>>>(deg, partial, N);
    scan_single<<<1, B, 0, stream>>>(partial, nb);
    scan_final<<<nb, B, 0, stream>>>(deg, partial, row_start, cursor, csr_src, N);
    scatter_kernel<<<gE, B, 0, stream>>>(src, dst, cursor, csr_src, E);

    // layer 1
    node1_kernel<<<gN, B, 0, stream>>>(x, W1, asrc1, adst1, h1, al_s1, al_d1, N);
    agg1_kernel<<<gW, B, 0, stream>>>(row_start, csr_src, al_s1, al_d1,
                                      (const float*)al_s1, h1, out1, N);
    // layer 2 (h2/al2s/al2d overwrite the now-dead h1 region)
    node2_kernel<<<gN, B, 0, stream>>>(out1, b1, W2, asrc2, adst2, h2, al2s, al2d, N);
    agg2_kernel<<<gW, B, 0, stream>>>(row_start, csr_src, al2s, al2d, h2, b2,
                                      (float*)d_out, N);
}